// Round 13
// baseline (112.392 us; speedup 1.0000x reference)
//
#include <hip/hip_runtime.h>
#include <math.h>

#define H 512
#define W 512
#define TBINS 180
#define RBINS 360
#define NPIX (H*W)

#define THETA_MIN (-1.5707963267948966f)
#define T_BIN ((float)(3.141592653589793 / 179.0))
#define R_MIN (-724.0773439350246f)
#define R_BIN ((float)(2.0 * 724.0773439350246 / 359.0))
#define THR_VAR 100.0f
#define WSIG 6.0f          // window: tail mass < 2e-9, << 1.16e-2 budget

#define NT 6               // rho tiles (64 cols each)
#define NBLK 1024          // prep blocks = record segments per tile
#define SCAP 256           // per-(block,tile) segment capacity (256 pix/block)
#define MPAD 192           // theta rows padded to 12 m-tiles of 16
#define GG 512             // gemm grid: EXACTLY 2 blocks/CU x 256 CU (resident)
#define NCKCAP 1024        // global chunk cap
#define RBLK 270           // reduce units: 6 tiles x 45 q-chunks

typedef short v8s __attribute__((ext_vector_type(8)));
typedef float v4f __attribute__((ext_vector_type(4)));

__device__ __forceinline__ float phi_cdf(float z) {
    return 0.5f * erfcf(-0.70710678118654752f * z);
}
__device__ __forceinline__ unsigned short f2bf(float f) {   // RNE f32->bf16
    unsigned u = __float_as_uint(f);
    return (unsigned short)((u + 0x7FFF + ((u >> 16) & 1)) >> 16);
}
__device__ __forceinline__ float bf2f(unsigned short b) {
    return __uint_as_float(((unsigned)b) << 16);
}

// R23: R12's A/B proved ~9-15us PER GRAPH NODE overhead (gemm dup = +15.0us
// with identical work; R10 memset node = +9.3us) — the invariant ~38us
// controllable was 3 nodes x ~10us boundary + ~8us work. Fix: 3 -> 2 nodes.
// gemm+reduce fused via device-scope atomic completion barrier (NOT coop
// launch — R8/R9; residency GUARANTEED: grid=512=2/CU x 256, launch_bounds
// caps VGPR, LDS 66KB forces exactly 2/CU). prep zeroes fin each launch so
// graph replay with poisoned ws is safe. Weights bit-identical; only the
// reduce tree width (16->8) changes the f32 add order.
__global__ void prep_kernel(const float* __restrict__ img,
                            const float* __restrict__ mask,
                            int* __restrict__ cblk,
                            float4* __restrict__ recs,
                            float* __restrict__ mvs,
                            int* __restrict__ fin) {
    __shared__ int lcnt[NT];
    int tid = threadIdx.x;
    int b = blockIdx.x;
    int gid = b * blockDim.x + tid;
    if (b == 0 && tid == 0) *fin = 0;     // re-arm barrier for this replay
    if (tid < NT) lcnt[tid] = 0;
    __syncthreads();

    int p = gid;
    int hi = p >> 9, wi = p & (W - 1);
    float mv = mask[p];

    int xm = max(hi - 1, 0), xp = min(hi + 1, H - 1);
    int ym = max(wi - 1, 0), yp = min(wi + 1, W - 1);
    const float* r0 = img + xm * W;
    const float* r1 = img + hi * W;
    const float* r2 = img + xp * W;
    float s00 = r0[ym], s01 = r0[wi], s02 = r0[yp];
    float s10 = r1[ym], s11 = r1[wi], s12 = r1[yp];
    float s20 = r2[ym], s21 = r2[wi], s22 = r2[yp];

    float alpha_s = (s20 + s21 + s22) - (s00 + s01 + s02);
    float beta_s  = (s02 + s12 + s22) - (s00 + s10 + s20);
    float gsum    = s00 + s01 + s02 + s10 + s11 + s12 + s20 + s21 + s22;

    float alpha = alpha_s * (1.0f / 6.0f) + 1e-6f;
    float beta  = beta_s  * (1.0f / 6.0f) + 1e-6f;
    float gamma = gsum * (1.0f / 9.0f);

    float cvals[3] = { s01, s11, s21 };
    float eps2 = 0.0f;
    #pragma unroll
    for (int ix = 0; ix < 3; ++ix) {
        float dx = (float)(ix - 1);
        float c = cvals[ix];
        #pragma unroll
        for (int iy = 0; iy < 3; ++iy) {
            float dy = (float)(iy - 1);
            float r = c - alpha * dy - beta * dx - gamma;
            eps2 += r * r;
        }
    }
    float noise_var = eps2 * (1.0f / 7.0f);
    float va = noise_var * (1.0f / 6.0f);
    float g2 = alpha * alpha + beta * beta;
    float var_theta = (beta * beta * va + alpha * alpha * va) / (g2 * g2);

    // conservative no-trig prefilter (x1.01 headroom), exact path after (R11)
    float x = (float)hi, y = (float)wi;
    float inv_g = rsqrtf(g2);
    float cta = fabsf(alpha) * inv_g;
    float sta = (alpha < 0.0f ? -beta : beta) * inv_g;
    float drho_a = -x * sta + y * cta;
    float var_rho_a = drho_a * drho_a * var_theta;
    bool maybe = (var_theta <= THR_VAR) && (var_rho_a <= THR_VAR * 1.01f) && (mv != 0.0f);

    int myNt[2] = { -1, -1 };
    int myPos[2];
    float4 rc;
    if (maybe) {
        float theta = atanf(beta / alpha);
        float ct = cosf(theta), st = sinf(theta);
        float rho = x * ct + y * st;
        float drho = -x * st + y * ct;
        float var_rho = drho * drho * var_theta;
        if (var_rho <= THR_VAR) {
            float sig_t = sqrtf(var_theta + 1e-12f);
            float sig_r = sqrtf(var_rho + 1e-12f);
            float radr = WSIG * sig_r;
            int rlo = max((int)floorf((rho - radr - R_MIN) / R_BIN - 0.5f), 0);
            int rhi = min((int)ceilf((rho + radr - R_MIN) / R_BIN + 0.5f), RBINS - 1);
            if (rhi >= rlo) {
                rc.x = theta; rc.y = 1.0f / sig_t; rc.z = rho; rc.w = 1.0f / sig_r;
                int nt0 = rlo >> 6, nt1 = rhi >> 6;   // window <= 32 bins -> <= 2 tiles
                for (int nt = nt0; nt <= nt1; ++nt) {
                    int k = nt - nt0;
                    myNt[k] = nt;
                    myPos[k] = atomicAdd(&lcnt[nt], 1);
                }
            }
        }
    }
    __syncthreads();
    if (tid < NT) cblk[tid * NBLK + b] = lcnt[tid];
    #pragma unroll
    for (int k = 0; k < 2; ++k) {
        if (myNt[k] >= 0) {
            int idx = (myNt[k] * NBLK + b) * SCAP + myPos[k];
            recs[idx] = rc;
            mvs[idx]  = mv;
        }
    }
}

__global__ void __launch_bounds__(512, 4)   // 4 waves/EU => 2 blocks/CU; grid 512 resident
gemmred_kernel(const float4* __restrict__ recs,
               const float* __restrict__ mvs,
               const int* __restrict__ cblk,
               int* __restrict__ fin,
               float* __restrict__ part,
               float4* __restrict__ out) {
    __shared__ __align__(16) unsigned short Ah[MPAD * 32], Al[MPAD * 32]; // [m][k]
    __shared__ __align__(16) unsigned short Bh[64 * 32],  Bl[64 * 32];    // [n][k]
    __shared__ float4 prec[32];
    __shared__ float  pmv[32];
    __shared__ int    pref[NT][NBLK];      // per-tile inclusive prefix (24 KB)
    __shared__ int    wsum[8][NT], woff[8][NT];
    __shared__ int    ckp[NT + 1], cnl[NT];
    __shared__ float4 sdata[512];          // reduce combine (8 KB)

    int bid = blockIdx.x;
    int tid = threadIdx.x;
    int lane = tid & 63, wv = tid >> 6;
    int nsub = wv & 3, mhalf = wv >> 2;

    // ---- one 6-wide scan: 2 counts/thread/tile, elementwise wave shfl ----
    int a0[NT], a1[NT], s[NT];
    #pragma unroll
    for (int t = 0; t < NT; ++t) {
        a0[t] = cblk[t * NBLK + 2 * tid];
        a1[t] = cblk[t * NBLK + 2 * tid + 1];
        s[t] = a0[t] + a1[t];
    }
    #pragma unroll
    for (int d = 1; d < 64; d <<= 1) {
        #pragma unroll
        for (int t = 0; t < NT; ++t) {
            int u = __shfl_up(s[t], d);
            if (lane >= d) s[t] += u;
        }
    }
    if (lane == 63) {
        #pragma unroll
        for (int t = 0; t < NT; ++t) wsum[wv][t] = s[t];
    }
    __syncthreads();
    if (tid == 0) {
        #pragma unroll
        for (int t = 0; t < NT; ++t) {
            int r = 0;
            #pragma unroll
            for (int i = 0; i < 8; ++i) { woff[i][t] = r; r += wsum[i][t]; }
        }
    }
    __syncthreads();
    #pragma unroll
    for (int t = 0; t < NT; ++t) {
        int base = woff[wv][t] + s[t];          // inclusive through 2*tid+1
        pref[t][2 * tid]     = base - a1[t];
        pref[t][2 * tid + 1] = base;
    }
    __syncthreads();
    if (tid == 0) {
        int r = 0;
        #pragma unroll
        for (int t = 0; t < NT; ++t) {
            ckp[t] = min(r, NCKCAP);
            int cn = pref[t][NBLK - 1];
            cnl[t] = cn;
            r += (cn + 31) >> 5;
        }
        ckp[NT] = min(r, NCKCAP);
    }
    __syncthreads();
    int nchunks = ckp[NT];

    int pix = tid & 31, g = tid >> 5;  // 16 groups x 32 pixels

    // ================= gemm: flat chunk list, <=1 chunk/block =================
    for (int c = bid; c < nchunks; c += GG) {
        if (c != bid) __syncthreads();

        int t = 0;
        #pragma unroll
        for (int i = 1; i < NT; ++i) if (c >= ckp[i]) t = i;
        int c0 = t * 64;
        int nbmax = min(63, RBINS - 1 - c0);
        int cn = cnl[t];
        int k0 = (c - ckp[t]) << 5;
        int k1 = min(k0 + 32, cn);

        if (tid < 32) {
            int r = k0 + tid;
            float4 rcv; rcv.x = 0.f; rcv.y = 0.f; rcv.z = 0.f; rcv.w = 0.f;
            float m = 0.f;
            if (r < k1) {
                int pos = 0;                       // first seg with pref > r
                #pragma unroll
                for (int st = 512; st >= 1; st >>= 1)
                    if (pos + st <= NBLK && pref[t][pos + st - 1] <= r) pos += st;
                int off = r - (pos ? pref[t][pos - 1] : 0);
                int idx = (t * NBLK + pos) * SCAP + off;
                rcv = recs[idx]; m = mvs[idx];
            }
            prec[tid] = rcv; pmv[tid] = m;
        }
        __syncthreads();

        // pack: rolling one-pass edge->diff->bf16 (R15)
        {
            float4 rc = prec[pix];
            float m = pmv[pix];
            bool live = (rc.y != 0.0f);
            if (g < 12) {
                int e0 = g << 4;
                float sigt = 1.0f / rc.y;
                int wx = max((int)floorf((rc.x - WSIG * sigt - THETA_MIN) / T_BIN - 0.5f), 0);
                int wy = min((int)ceilf((rc.x + WSIG * sigt - THETA_MIN) / T_BIN + 0.5f), TBINS - 1);
                int sb = e0 * 32 + pix;
                float prev = 0.0f;
                #pragma unroll 1
                for (int i = 0; i <= 16; ++i) {
                    int e = e0 + i;
                    float val;
                    if (!live || e < wx) val = 0.0f;
                    else if (e > wy + 1) val = 1.0f;
                    else {
                        float edge = THETA_MIN + ((float)e - 0.5f) * T_BIN;
                        val = phi_cdf((edge - rc.x) * rc.y);
                    }
                    if (i > 0) {
                        float wt = (val - prev) * m;
                        unsigned short hb = f2bf(wt);
                        Ah[sb + (i - 1) * 32] = hb;
                        Al[sb + (i - 1) * 32] = f2bf(wt - bf2f(hb));
                    }
                    prev = val;
                }
            } else {
                int n0 = (g - 12) << 4;
                float sigr = 1.0f / rc.w;
                int wz = max((int)floorf((rc.z - WSIG * sigr - R_MIN) / R_BIN - 0.5f) - c0, 0);
                int ww = min((int)ceilf((rc.z + WSIG * sigr - R_MIN) / R_BIN + 0.5f) - c0, nbmax);
                int sb = n0 * 32 + pix;
                float prev = 0.0f;
                #pragma unroll 1
                for (int i = 0; i <= 16; ++i) {
                    int n = n0 + i;
                    float val;
                    if (!live || n < wz) val = 0.0f;
                    else if (n > ww + 1) val = 1.0f;
                    else {
                        float edge = R_MIN + ((float)(c0 + n) - 0.5f) * R_BIN;
                        val = phi_cdf((edge - rc.z) * rc.w);
                    }
                    if (i > 0) {
                        float wr = val - prev;
                        unsigned short hb = f2bf(wr);
                        Bh[sb + (i - 1) * 32] = hb;
                        Bl[sb + (i - 1) * 32] = f2bf(wr - bf2f(hb));
                    }
                    prev = val;
                }
            }
        }
        __syncthreads();

        v4f zero = {0.f, 0.f, 0.f, 0.f};
        v4f acc[6];
        #pragma unroll
        for (int i = 0; i < 6; ++i) acc[i] = zero;

        int kq = (lane >> 4) * 8;
        int mr = lane & 15;
        v8s bh = *((__shared__ v8s*)&Bh[(nsub * 16 + mr) * 32 + kq]);
        v8s bl = *((__shared__ v8s*)&Bl[(nsub * 16 + mr) * 32 + kq]);
        #pragma unroll
        for (int mt = 0; mt < 6; ++mt) {
            int mbase = (mhalf * 6 + mt) * 16;
            v8s ah = *((__shared__ v8s*)&Ah[(mbase + mr) * 32 + kq]);
            v8s al = *((__shared__ v8s*)&Al[(mbase + mr) * 32 + kq]);
            acc[mt] = __builtin_amdgcn_mfma_f32_16x16x32_bf16(ah, bh, acc[mt], 0, 0, 0);
            acc[mt] = __builtin_amdgcn_mfma_f32_16x16x32_bf16(ah, bl, acc[mt], 0, 0, 0);
            acc[mt] = __builtin_amdgcn_mfma_f32_16x16x32_bf16(al, bh, acc[mt], 0, 0, 0);
        }

        float* slab = part + (size_t)c * (MPAD * 64);
        int col = nsub * 16 + (lane & 15);
        int rq = (lane >> 4) * 4;
        #pragma unroll
        for (int mt = 0; mt < 6; ++mt) {
            int rbase = (mhalf * 6 + mt) * 16 + rq;
            #pragma unroll
            for (int r = 0; r < 4; ++r)
                slab[(rbase + r) * 64 + col] = acc[mt][r];
        }
    }

    // ============ completion barrier (all 512 blocks resident) ============
    __syncthreads();                       // drains this block's slab stores
    if (tid == 0) {
        __threadfence();                   // device-scope release (L2 wb)
        __hip_atomic_fetch_add(fin, 1, __ATOMIC_RELAXED, __HIP_MEMORY_SCOPE_AGENT);
    }
    if (bid >= RBLK) return;               // non-reduce blocks exit, free CUs

    if (tid == 0) {
        while (__hip_atomic_load(fin, __ATOMIC_RELAXED, __HIP_MEMORY_SCOPE_AGENT) < GG)
            __builtin_amdgcn_s_sleep(8);
        __threadfence();                   // device-scope acquire (L2/L1 inv)
    }
    __syncthreads();

    // ================= reduce (blocks 0..269, 512 threads) =================
    {
        int t = bid / 45, qc = bid % 45;
        int qi = tid & 63, jg = tid >> 6;          // 8 slab-groups
        int q = qc * 64 + qi;                      // [0,2880)
        int n0 = ckp[t], n1 = ckp[t + 1];
        const float4* p4 = (const float4*)part;
        float4 sv; sv.x = 0.f; sv.y = 0.f; sv.z = 0.f; sv.w = 0.f;
        #pragma unroll 4
        for (int j = n0 + jg; j < n1; j += 8) {
            float4 v = p4[(size_t)j * (MPAD * 16) + q];
            sv.x += v.x; sv.y += v.y; sv.z += v.z; sv.w += v.w;
        }
        sdata[tid] = sv;
        __syncthreads();
        #pragma unroll
        for (int h = 4; h >= 1; h >>= 1) {
            if (jg < h) {
                float4 o = sdata[(jg + h) * 64 + qi];
                sv.x += o.x; sv.y += o.y; sv.z += o.z; sv.w += o.w;
                sdata[tid] = sv;
            }
            __syncthreads();
        }
        if (jg == 0) {
            int row = q >> 4, c4 = q & 15;
            if (!(t == 5 && c4 >= 10))             // cols 360..383 don't exist
                out[row * 90 + t * 16 + c4] = sv;  // (row*360 + t*64)/4
        }
    }
}

extern "C" void kernel_launch(void* const* d_in, const int* in_sizes, int n_in,
                              void* d_out, int out_size, void* d_ws, size_t ws_size,
                              hipStream_t stream) {
    const float* img  = (const float*)d_in[0];
    const float* mask = (const float*)d_in[1];
    float4* out = (float4*)d_out;

    // ws layout (16B-aligned):
    //   cblk @0     : NT*NBLK*4        = 24576 B  (pad to 32768)
    //   recs        : NT*NBLK*SCAP*16  = 25165824 B
    //   mvs         : NT*NBLK*SCAP*4   = 6291456 B
    //   fin         : 4 B              (pad to 1024)
    //   part        : NCKCAP*MPAD*64*4 = 50331648 B   (~82 MB total)
    char* ws = (char*)d_ws;
    size_t off_recs = 32768;
    size_t off_mvs  = off_recs + (size_t)NT * NBLK * SCAP * 16;
    size_t off_fin  = off_mvs + (size_t)NT * NBLK * SCAP * 4;
    size_t off_part = off_fin + 1024;

    int*    cblk = (int*)ws;
    float4* recs = (float4*)(ws + off_recs);
    float*  mvs  = (float*)(ws + off_mvs);
    int*    fin  = (int*)(ws + off_fin);
    float*  part = (float*)(ws + off_part);

    prep_kernel<<<NPIX / 256, 256, 0, stream>>>(img, mask, cblk, recs, mvs, fin);
    gemmred_kernel<<<GG, 512, 0, stream>>>(recs, mvs, cblk, fin, part, out);
}

// Round 14
// 77.587 us; speedup vs baseline: 1.4486x; 1.4486x over previous
//
#include <hip/hip_runtime.h>
#include <math.h>

#define H 512
#define W 512
#define TBINS 180
#define RBINS 360
#define NPIX (H*W)

#define THETA_MIN (-1.5707963267948966f)
#define T_BIN ((float)(3.141592653589793 / 179.0))
#define R_MIN (-724.0773439350246f)
#define R_BIN ((float)(2.0 * 724.0773439350246 / 359.0))
#define THR_VAR 100.0f
#define WSIG 6.0f          // window: tail mass < 2e-9, << 1.16e-2 budget

#define NT 6               // rho tiles (64 cols each)
#define KB 256             // gemm blocks per tile (tail-spread; grid-stride)
#define NBLK 1024          // prep blocks = record segments per tile
#define SCAP 256           // per-(block,tile) segment capacity (256 pix/block)
#define MPAD 192           // theta rows padded to 12 m-tiles of 16

typedef short v8s __attribute__((ext_vector_type(8)));
typedef float v4f __attribute__((ext_vector_type(4)));

__device__ __forceinline__ float phi_cdf(float z) {
    return 0.5f * erfcf(-0.70710678118654752f * z);
}
__device__ __forceinline__ unsigned short f2bf(float f) {   // RNE f32->bf16
    unsigned u = __float_as_uint(f);
    return (unsigned short)((u + 0x7FFF + ((u >> 16) & 1)) >> 16);
}
__device__ __forceinline__ float bf2f(unsigned short b) {
    return __uint_as_float(((unsigned)b) << 16);
}

// R24 = R7 restored verbatim (session best, 77.8us). Session ledger:
// - 3 direct node-cost measurements: +9.3us (R10 memset node), +15.0us
//   (R12 duplicate warm gemm), +31us (R13 in-kernel barrier fusion).
// - Cold gemm-class kernel = 42-55us wall with ALL pipes idle (R2/R13
//   direct); warm identical = 15us (R12 A/B) -> the invariant ~37us
//   controllable is post-fill cache state + per-node costs, not code.
// - 7 intra-kernel rewrites neutral; coop launch fails graph capture
//   (R8/R9); barrier fusion regresses (R13).
// Floor: 41 (fill @80% HBM peak) + 3 x ~10 (nodes) + ~8 (work) = 78-81us.
__global__ void prep_kernel(const float* __restrict__ img,
                            const float* __restrict__ mask,
                            int* __restrict__ cblk,
                            float4* __restrict__ recs,
                            float* __restrict__ mvs) {
    __shared__ int lcnt[NT];
    int tid = threadIdx.x;
    int b = blockIdx.x;
    int gid = b * blockDim.x + tid;
    if (tid < NT) lcnt[tid] = 0;
    __syncthreads();

    int p = gid;
    int hi = p >> 9, wi = p & (W - 1);
    float mv = mask[p];

    int xm = max(hi - 1, 0), xp = min(hi + 1, H - 1);
    int ym = max(wi - 1, 0), yp = min(wi + 1, W - 1);
    const float* r0 = img + xm * W;
    const float* r1 = img + hi * W;
    const float* r2 = img + xp * W;
    float s00 = r0[ym], s01 = r0[wi], s02 = r0[yp];
    float s10 = r1[ym], s11 = r1[wi], s12 = r1[yp];
    float s20 = r2[ym], s21 = r2[wi], s22 = r2[yp];

    float alpha_s = (s20 + s21 + s22) - (s00 + s01 + s02);
    float beta_s  = (s02 + s12 + s22) - (s00 + s10 + s20);
    float gsum    = s00 + s01 + s02 + s10 + s11 + s12 + s20 + s21 + s22;

    float alpha = alpha_s * (1.0f / 6.0f) + 1e-6f;
    float beta  = beta_s  * (1.0f / 6.0f) + 1e-6f;
    float gamma = gsum * (1.0f / 9.0f);

    float cvals[3] = { s01, s11, s21 };
    float eps2 = 0.0f;
    #pragma unroll
    for (int ix = 0; ix < 3; ++ix) {
        float dx = (float)(ix - 1);
        float c = cvals[ix];
        #pragma unroll
        for (int iy = 0; iy < 3; ++iy) {
            float dy = (float)(iy - 1);
            float r = c - alpha * dy - beta * dx - gamma;
            eps2 += r * r;
        }
    }
    float noise_var = eps2 * (1.0f / 7.0f);
    float va = noise_var * (1.0f / 6.0f);
    float g2 = alpha * alpha + beta * beta;
    float var_theta = (beta * beta * va + alpha * alpha * va) / (g2 * g2);

    // conservative no-trig prefilter (x1.01 headroom), exact path after
    float x = (float)hi, y = (float)wi;
    float inv_g = rsqrtf(g2);
    float cta = fabsf(alpha) * inv_g;
    float sta = (alpha < 0.0f ? -beta : beta) * inv_g;
    float drho_a = -x * sta + y * cta;
    float var_rho_a = drho_a * drho_a * var_theta;
    bool maybe = (var_theta <= THR_VAR) && (var_rho_a <= THR_VAR * 1.01f) && (mv != 0.0f);

    int myNt[2] = { -1, -1 };
    int myPos[2];
    float4 rc;
    if (maybe) {
        float theta = atanf(beta / alpha);
        float ct = cosf(theta), st = sinf(theta);
        float rho = x * ct + y * st;
        float drho = -x * st + y * ct;
        float var_rho = drho * drho * var_theta;
        if (var_rho <= THR_VAR) {
            float sig_t = sqrtf(var_theta + 1e-12f);
            float sig_r = sqrtf(var_rho + 1e-12f);
            float radr = WSIG * sig_r;
            int rlo = max((int)floorf((rho - radr - R_MIN) / R_BIN - 0.5f), 0);
            int rhi = min((int)ceilf((rho + radr - R_MIN) / R_BIN + 0.5f), RBINS - 1);
            if (rhi >= rlo) {
                rc.x = theta; rc.y = 1.0f / sig_t; rc.z = rho; rc.w = 1.0f / sig_r;
                int nt0 = rlo >> 6, nt1 = rhi >> 6;   // window <= 32 bins -> <= 2 tiles
                for (int nt = nt0; nt <= nt1; ++nt) {
                    int k = nt - nt0;
                    myNt[k] = nt;
                    myPos[k] = atomicAdd(&lcnt[nt], 1);
                }
            }
        }
    }
    __syncthreads();
    if (tid < NT) cblk[tid * NBLK + b] = lcnt[tid];
    #pragma unroll
    for (int k = 0; k < 2; ++k) {
        if (myNt[k] >= 0) {
            int idx = (myNt[k] * NBLK + b) * SCAP + myPos[k];
            recs[idx] = rc;
            mvs[idx]  = mv;
        }
    }
}

// GEMM M=192(pad) N=64/tile, grid-stride over FULL 32-record chunks; packed
// view via LDS prefix scan + binary search; KB=256 -> hot tile 1 chunk/block.
__global__ void __launch_bounds__(512)
gemm_kernel(const float4* __restrict__ recs,
            const float* __restrict__ mvs,
            const int* __restrict__ cblk,
            int* __restrict__ nw,
            float* __restrict__ part) {
    __shared__ __align__(16) unsigned short Ah[MPAD * 32], Al[MPAD * 32]; // [m][k]
    __shared__ __align__(16) unsigned short Bh[64 * 32],  Bl[64 * 32];    // [n][k]
    __shared__ float4 prec[2][32];
    __shared__ float  pmv[2][32];
    __shared__ int    pref[NBLK];       // inclusive prefix of per-block counts
    __shared__ int    wsum[8], woff[8];

    int nt = blockIdx.x % NT, kb = blockIdx.x / NT;
    int tid = threadIdx.x;
    int lane = tid & 63, wv = tid >> 6;
    int nsub = wv & 3, mhalf = wv >> 2;
    int c0 = nt * 64;
    int nbmax = min(63, RBINS - 1 - c0);

    // ---- prefix scan: 1024 counts, 2 per thread, wave shfl + 8-wave fixup ----
    const int* cb = cblk + nt * NBLK;
    int a0 = cb[2 * tid], a1 = cb[2 * tid + 1];
    int s = a0 + a1;
    #pragma unroll
    for (int d = 1; d < 64; d <<= 1) {
        int u = __shfl_up(s, d);
        if (lane >= d) s += u;
    }
    if (lane == 63) wsum[wv] = s;
    __syncthreads();
    if (tid == 0) {
        int r = 0;
        #pragma unroll
        for (int i = 0; i < 8; ++i) { woff[i] = r; r += wsum[i]; }
    }
    __syncthreads();
    int base = woff[wv] + s;            // inclusive through element 2*tid+1
    pref[2 * tid]     = base - a1;
    pref[2 * tid + 1] = base;
    __syncthreads();

    int cn = pref[NBLK - 1];
    int nck = (cn + 31) >> 5;          // full 32-wide chunks
    if (kb == 0 && tid == 0) nw[nt] = min(nck, KB);   // slab count for reduce
    if (kb >= nck) return;             // idle block: writes no slab

    v4f zero = {0.f, 0.f, 0.f, 0.f};
    v4f acc[6];
    #pragma unroll
    for (int i = 0; i < 6; ++i) acc[i] = zero;

    const float4* rb = recs + (size_t)nt * NBLK * SCAP;
    const float*  mb = mvs + (size_t)nt * NBLK * SCAP;

    int pix = tid & 31, g = tid >> 5;  // 16 groups x 32 pixels

    // prologue: blocking search+load of chunk kb into prec[0]
    if (tid < 32) {
        int r = (kb << 5) + tid;
        float4 rcv; rcv.x = 0.f; rcv.y = 0.f; rcv.z = 0.f; rcv.w = 0.f;
        float m = 0.f;
        if (r < min((kb << 5) + 32, cn)) {
            int pos = 0;
            #pragma unroll
            for (int st = 512; st >= 1; st >>= 1)
                if (pos + st <= NBLK && pref[pos + st - 1] <= r) pos += st;
            int off = r - (pos ? pref[pos - 1] : 0);
            int idx = pos * SCAP + off;
            rcv = rb[idx]; m = mb[idx];
        }
        prec[0][tid] = rcv; pmv[0][tid] = m;
    }

    int parity = 0;
    for (int ck = kb; ck < nck; ck += KB, parity ^= 1) {
        __syncthreads();       // prec[parity] ready; A/B tiles consumed (prev iter)

        // issue next chunk's search + record loads into REGISTERS (no wait here)
        bool do_pf = (tid < 32) && (ck + KB < nck);
        float4 pf_rc; pf_rc.x = 0.f; pf_rc.y = 0.f; pf_rc.z = 0.f; pf_rc.w = 0.f;
        float pf_m = 0.f;
        if (do_pf) {
            int r = ((ck + KB) << 5) + tid;
            if (r < min(((ck + KB) << 5) + 32, cn)) {
                int pos = 0;
                #pragma unroll
                for (int st = 512; st >= 1; st >>= 1)
                    if (pos + st <= NBLK && pref[pos + st - 1] <= r) pos += st;
                int off = r - (pos ? pref[pos - 1] : 0);
                int idx = pos * SCAP + off;
                pf_rc = rb[idx]; pf_m = mb[idx];
            }
        }

        // pack: rolling one-pass edge->diff->bf16 from prec[parity]
        {
            float4 rc = prec[parity][pix];
            float m = pmv[parity][pix];
            bool live = (rc.y != 0.0f);
            if (g < 12) {
                int e0 = g << 4;
                float sigt = 1.0f / rc.y;
                int wx = max((int)floorf((rc.x - WSIG * sigt - THETA_MIN) / T_BIN - 0.5f), 0);
                int wy = min((int)ceilf((rc.x + WSIG * sigt - THETA_MIN) / T_BIN + 0.5f), TBINS - 1);
                int sb = e0 * 32 + pix;
                float prev = 0.0f;
                #pragma unroll 1
                for (int i = 0; i <= 16; ++i) {
                    int e = e0 + i;
                    float val;
                    if (!live || e < wx) val = 0.0f;
                    else if (e > wy + 1) val = 1.0f;
                    else {
                        float edge = THETA_MIN + ((float)e - 0.5f) * T_BIN;
                        val = phi_cdf((edge - rc.x) * rc.y);
                    }
                    if (i > 0) {
                        float wt = (val - prev) * m;
                        unsigned short hb = f2bf(wt);
                        Ah[sb + (i - 1) * 32] = hb;
                        Al[sb + (i - 1) * 32] = f2bf(wt - bf2f(hb));
                    }
                    prev = val;
                }
            } else {
                int n0 = (g - 12) << 4;
                float sigr = 1.0f / rc.w;
                int wz = max((int)floorf((rc.z - WSIG * sigr - R_MIN) / R_BIN - 0.5f) - c0, 0);
                int ww = min((int)ceilf((rc.z + WSIG * sigr - R_MIN) / R_BIN + 0.5f) - c0, nbmax);
                int sb = n0 * 32 + pix;
                float prev = 0.0f;
                #pragma unroll 1
                for (int i = 0; i <= 16; ++i) {
                    int n = n0 + i;
                    float val;
                    if (!live || n < wz) val = 0.0f;
                    else if (n > ww + 1) val = 1.0f;
                    else {
                        float edge = R_MIN + ((float)(c0 + n) - 0.5f) * R_BIN;
                        val = phi_cdf((edge - rc.z) * rc.w);
                    }
                    if (i > 0) {
                        float wr = val - prev;
                        unsigned short hb = f2bf(wr);
                        Bh[sb + (i - 1) * 32] = hb;
                        Bl[sb + (i - 1) * 32] = f2bf(wr - bf2f(hb));
                    }
                    prev = val;
                }
            }
        }
        __syncthreads();       // A/B tiles ready

        // write-late: park prefetched records in LDS
        if (do_pf) { prec[parity ^ 1][tid] = pf_rc; pmv[parity ^ 1][tid] = pf_m; }

        int kq = (lane >> 4) * 8;
        int mr = lane & 15;
        v8s bh = *((__shared__ v8s*)&Bh[(nsub * 16 + mr) * 32 + kq]);
        v8s bl = *((__shared__ v8s*)&Bl[(nsub * 16 + mr) * 32 + kq]);
        #pragma unroll
        for (int mt = 0; mt < 6; ++mt) {
            int mbase = (mhalf * 6 + mt) * 16;
            v8s ah = *((__shared__ v8s*)&Ah[(mbase + mr) * 32 + kq]);
            v8s al = *((__shared__ v8s*)&Al[(mbase + mr) * 32 + kq]);
            acc[mt] = __builtin_amdgcn_mfma_f32_16x16x32_bf16(ah, bh, acc[mt], 0, 0, 0);
            acc[mt] = __builtin_amdgcn_mfma_f32_16x16x32_bf16(ah, bl, acc[mt], 0, 0, 0);
            acc[mt] = __builtin_amdgcn_mfma_f32_16x16x32_bf16(al, bh, acc[mt], 0, 0, 0);
        }
    }

    // drain: plain coalesced stores to this block's private slab (no atomics).
    // C/D layout: col=lane&15 (n), row=(lane>>4)*4+reg (m)  [verified R6-R10]
    float* slab = part + (size_t)(nt * KB + kb) * (MPAD * 64);
    int col = nsub * 16 + (lane & 15);
    int rq = (lane >> 4) * 4;
    #pragma unroll
    for (int mt = 0; mt < 6; ++mt) {
        int rbase = (mhalf * 6 + mt) * 16 + rq;
        #pragma unroll
        for (int r = 0; r < 4; ++r)
            slab[(rbase + r) * 64 + col] = acc[mt][r];
    }
}

// Slab reduce with TLP: 270 blocks x 1024 threads (16 waves); jg=tid>>6
// splits the <=nw slabs 16 ways (unroll-4 ILP), 4-level LDS tree over jg.
// Writes every out cell exactly once -> no out zeroing anywhere.
__global__ void __launch_bounds__(1024)
reduce_kernel(const float4* __restrict__ part, const int* __restrict__ nw,
              float4* __restrict__ out) {
    __shared__ float4 sdata[1024];
    int t = blockIdx.x / 45;
    int tid = threadIdx.x;
    int qi = tid & 63, jg = tid >> 6;          // 16 slab-groups
    int q = (blockIdx.x % 45) * 64 + qi;       // [0,2880): row=q>>4, c4=q&15
    int n = nw[t];
    const float4* p = part + (size_t)t * KB * (MPAD * 16) + q;
    float4 s; s.x = 0.f; s.y = 0.f; s.z = 0.f; s.w = 0.f;
    #pragma unroll 4
    for (int j = jg; j < n; j += 16) {
        float4 v = p[(size_t)j * (MPAD * 16)];
        s.x += v.x; s.y += v.y; s.z += v.z; s.w += v.w;
    }
    sdata[tid] = s;
    __syncthreads();
    #pragma unroll
    for (int h = 8; h >= 1; h >>= 1) {
        if (jg < h) {
            float4 o = sdata[(jg + h) * 64 + qi];
            s.x += o.x; s.y += o.y; s.z += o.z; s.w += o.w;
            sdata[tid] = s;
        }
        __syncthreads();
    }
    if (jg == 0) {
        int row = q >> 4, c4 = q & 15;
        if (!(t == 5 && c4 >= 10))             // cols 360..383 don't exist
            out[row * 90 + t * 16 + c4] = s;   // (row*360 + t*64)/4
    }
}

extern "C" void kernel_launch(void* const* d_in, const int* in_sizes, int n_in,
                              void* d_out, int out_size, void* d_ws, size_t ws_size,
                              hipStream_t stream) {
    const float* img  = (const float*)d_in[0];
    const float* mask = (const float*)d_in[1];
    float* out = (float*)d_out;

    // ws layout (all offsets 16B-aligned):
    //   cblk @0              : NT*NBLK*4       = 24576 B   (pad to 32768)
    //   recs @32768          : NT*NBLK*SCAP*16 = 25165824 B
    //   mvs                  : NT*NBLK*SCAP*4  = 6291456 B
    //   nw                   : NT*4            (pad to 1024)
    //   part                 : NT*KB*MPAD*64*4 = 75497472 B   (~107 MB total)
    char* ws = (char*)d_ws;
    size_t off_recs = 32768;
    size_t off_mvs  = off_recs + (size_t)NT * NBLK * SCAP * 16;
    size_t off_nw   = off_mvs + (size_t)NT * NBLK * SCAP * 4;
    size_t off_part = off_nw + 1024;

    int*    cblk = (int*)ws;
    float4* recs = (float4*)(ws + off_recs);
    float*  mvs  = (float*)(ws + off_mvs);
    int*    nw   = (int*)(ws + off_nw);
    float*  part = (float*)(ws + off_part);

    prep_kernel<<<NPIX / 256, 256, 0, stream>>>(img, mask, cblk, recs, mvs);
    gemm_kernel<<<NT * KB, 512, 0, stream>>>(recs, mvs, cblk, nw, part);
    reduce_kernel<<<270, 1024, 0, stream>>>((const float4*)part, nw, (float4*)out);
}